// Round 1
// baseline (252.667 us; speedup 1.0000x reference)
//
#include <hip/hip_runtime.h>

// QFD2Loss: mean over B rows of Q A Q^T, Q = D - softmax(logit), A[j,k]=1-|j-k|/31.
// Identity (exact): QAQ^T = S^2 + (2/31)*(sum_{t<31} P_t^2 - S*sum_{t<31} P_t),
// P_t = prefix sums of Q, S = P_31.
//
// R7: 8-LANE COOPERATIVE ROWS, ZERO LDS, ZERO BARRIERS.
// R5/R6 staged coalesced loads through an LDS transpose so each lane owned a
// full row; the block-wide barrier pairs (each draining vmcnt(0)) phase-locked
// the 8 resident waves/CU and capped read BW at ~3.6 TB/s while the harness
// fills hit 6.9 TB/s at 9.5% occupancy. R6's register prefetch changed nothing
// (247.3 -> 246.0) -- the coupling was the barriers, not per-wave latency.
// Now each row is computed by an 8-lane group (4 bins/lane): one coalesced
// float4 load delivers 8 complete rows to the right lanes directly, the
// softmax/prefix math uses ~10 width-8 shuffles per 8 rows, and sP/sP2
// reductions fold into the global accumulator (no cross-lane ops needed).
// No LDS -> all 4096 waves resident, 16 loads in flight per wave.

#define L_BINS  32
#define NTHREAD 256
#define NBLOCKS 1024   // 4096 waves; 64 rows/wave/iter; 4 iters at B=1M
#define UNROLL  8      // row-groups (8 rows each) per wave per iteration

typedef float vfloat4 __attribute__((ext_vector_type(4)));

__device__ __forceinline__ vfloat4 nt_load4(const float* p) {
    return __builtin_nontemporal_load((const vfloat4*)p);
}

__global__ __launch_bounds__(NTHREAD) void qfd2_main(const float* __restrict__ logit,
                                                     const float* __restrict__ D,
                                                     float* __restrict__ partial,
                                                     int rows) {
    const int t    = threadIdx.x;
    const int lane = t & 63;
    const int s    = lane & 7;    // sub-lane within 8-lane row group
    const int g    = lane >> 3;   // row group 0..7 within wave
    const int wid  = blockIdx.x * (NTHREAD / 64) + (t >> 6);
    const int nwaves = NBLOCKS * (NTHREAD / 64);

    const float w3 = (s == 7) ? 0.0f : 1.0f;  // lane 7 holds t=31: exclude from sP/sP2

    float acc = 0.0f;

    for (int base = wid * 64; base < rows; base += nwaves * 64) {
        // ---- issue all 16 coalesced loads up front (16 KB in flight/wave) ----
        vfloat4 vz[UNROLL], vd[UNROLL];
#pragma unroll
        for (int u = 0; u < UNROLL; ++u) {
            int row = base + u * 8 + g;
            int crow = row < rows ? row : rows - 1;          // clamp; masked below
            const size_t off = (size_t)crow * L_BINS + s * 4;
            vz[u] = nt_load4(logit + off);
            vd[u] = nt_load4(D + off);
        }

        // ---- compute 8 independent row groups (ILP hides shuffle latency) ----
#pragma unroll
        for (int u = 0; u < UNROLL; ++u) {
            const bool valid = (base + u * 8 + g) < rows;
            const vfloat4 z = vz[u], d = vd[u];

            // row max (3 dep shuffles, width 8)
            float m = fmaxf(fmaxf(z.x, z.y), fmaxf(z.z, z.w));
            m = fmaxf(m, __shfl_xor(m, 1, 8));
            m = fmaxf(m, __shfl_xor(m, 2, 8));
            m = fmaxf(m, __shfl_xor(m, 4, 8));

            // exp + row sum
            const float e0 = __expf(z.x - m), e1 = __expf(z.y - m);
            const float e2 = __expf(z.z - m), e3 = __expf(z.w - m);
            float sum = (e0 + e1) + (e2 + e3);
            sum += __shfl_xor(sum, 1, 8);
            sum += __shfl_xor(sum, 2, 8);
            sum += __shfl_xor(sum, 4, 8);
            const float rs = 1.0f / sum;

            // Q = D - p, local inclusive prefix over this lane's 4 bins
            const float q0 = d.x - e0 * rs, q1 = d.y - e1 * rs;
            const float q2 = d.z - e2 * rs, q3 = d.w - e3 * rs;
            const float p0 = q0, p1 = p0 + q1, p2 = p1 + q2, p3 = p2 + q3;

            // Hillis-Steele inclusive scan of lane totals across the group
            const float T = p3;
            float inc = T, tmp;
            tmp = __shfl_up(inc, 1, 8); if (s >= 1) inc += tmp;
            tmp = __shfl_up(inc, 2, 8); if (s >= 2) inc += tmp;
            tmp = __shfl_up(inc, 4, 8); if (s >= 4) inc += tmp;
            const float off_ = inc - T;              // exclusive prefix offset
            const float S    = __shfl(inc, 7, 8);    // row total = P_31

            // global prefix sums at this lane's 4 positions
            const float P0 = off_ + p0, P1 = off_ + p1;
            const float P2 = off_ + p2, P3 = off_ + p3;

            // lane-local pieces of sP, sP2 (t<=30); no reduce needed -- folds
            // into the global accumulator (every lane adds S^2/8, exact: *2^-3)
            const float sPl  = ((P0 + P1) + P2) + w3 * P3;
            const float sP2l = fmaf(P0, P0, fmaf(P1, P1, fmaf(P2, P2, w3 * P3 * P3)));
            const float c    = (2.0f / 31.0f) * (sP2l - S * sPl) + 0.125f * (S * S);
            acc += valid ? c : 0.0f;
        }
    }

    // ---- wave + block reduction, one partial per block ----
#pragma unroll
    for (int msk = 1; msk < 64; msk <<= 1) acc += __shfl_xor(acc, msk);

    __shared__ float wpart[NTHREAD / 64];
    if ((t & 63) == 0) wpart[t >> 6] = acc;
    __syncthreads();
    if (t == 0)
        partial[blockIdx.x] = (wpart[0] + wpart[1]) + (wpart[2] + wpart[3]);
}

__global__ __launch_bounds__(256) void qfd2_fin(const float* __restrict__ partial,
                                                float* __restrict__ out,
                                                int nblocks, int rows) {
    double a = 0.0;
    for (int i = threadIdx.x; i < nblocks; i += 256) a += (double)partial[i];
#pragma unroll
    for (int msk = 1; msk < 64; msk <<= 1) a += __shfl_xor(a, msk);

    __shared__ double wp[4];
    if ((threadIdx.x & 63) == 0) wp[threadIdx.x >> 6] = a;
    __syncthreads();
    if (threadIdx.x == 0)
        out[0] = (float)(((wp[0] + wp[1]) + (wp[2] + wp[3])) / (double)rows);
}

extern "C" void kernel_launch(void* const* d_in, const int* in_sizes, int n_in,
                              void* d_out, int out_size, void* d_ws, size_t ws_size,
                              hipStream_t stream) {
    const float* logit = (const float*)d_in[0];
    const float* D     = (const float*)d_in[1];
    float* out         = (float*)d_out;
    float* partial     = (float*)d_ws;

    const int rows = in_sizes[0] / L_BINS;  // 1048576

    qfd2_main<<<NBLOCKS, NTHREAD, 0, stream>>>(logit, D, partial, rows);
    qfd2_fin<<<1, 256, 0, stream>>>(partial, out, NBLOCKS, rows);
}